// Round 5
// baseline (48.065 us; speedup 1.0000x reference)
//
#include <hip/hip_runtime.h>
#include <math.h>

#define B_    32
#define PPB   256
#define N_    (B_*PPB)     // 8192 proposals / padded slots
#define M_    128
#define LANG_ 256
#define H_    128
#define EPS_  1e-5f
#define MC    16           // columns per block
#define NBLK  (N_/MC)      // 512 blocks

typedef __attribute__((ext_vector_type(8))) short s16x8;
typedef __attribute__((ext_vector_type(4))) float f32x4;

static __device__ __forceinline__ unsigned short f2bf(float x) {
  unsigned int u = __float_as_uint(x);
  unsigned int r = (u + 0x7fff + ((u >> 16) & 1)) >> 16;
  return (unsigned short)r;
}
static __device__ __forceinline__ float bf2f(unsigned short h) {
  return __uint_as_float(((unsigned int)h) << 16);
}

// ---------------------------------------------------------------------------
// ONE fused kernel. 512 blocks x 256 threads, 16 output columns per block.
// Each block redundantly computes its own slice of the batch/rank mapping
// (membership bitmask + wave scan), the lang projection for its batch, BN
// folds, then the 3-layer MFMA MLP (hi/lo bf16 split, exact fp32-grade).
// ---------------------------------------------------------------------------
__global__ __launch_bounds__(256, 2) void k_fused(
    const float* __restrict__ feats,
    const int* __restrict__ pidx, const int* __restrict__ poff,
    const int* __restrict__ boff, const float* __restrict__ langg,
    const float* __restrict__ Wf, const float* __restrict__ bf,
    const float* __restrict__ W1, const float* __restrict__ b1,
    const float* __restrict__ g1, const float* __restrict__ be1,
    const float* __restrict__ rm1, const float* __restrict__ rv1,
    const float* __restrict__ W2, const float* __restrict__ b2,
    const float* __restrict__ g2, const float* __restrict__ be2,
    const float* __restrict__ rm2, const float* __restrict__ rv2,
    const float* __restrict__ W3, const float* __restrict__ b3,
    float* __restrict__ out)
{
  __shared__ s16x8 XbHi[256];      // [sg16][n16] frags (4 KB)
  __shared__ s16x8 XbLo[256];      // (4 KB)
  __shared__ float pbuf[1024];     // [0]=bf+lp,[1]=b1,[2]=s1,[3]=t1,[4]=b2,[5]=s2,[6]=t2,[7]=W3
  __shared__ float outp[64];
  __shared__ int   sSrow[MC];
  __shared__ int   wtot[4];

  const int tid = threadIdx.x;
  const int lane = tid & 63, wid = tid >> 6;
  const int o16 = lane & 15, g = lane >> 4;
  const int q0 = blockIdx.x * MC;
  const int b = q0 >> 8;           // 16 blocks per batch
  const int r0 = q0 & 255;         // within-batch column window start

  if (tid < MC) sSrow[tid] = -1;

  // ---- membership mask for this block's batch (32 proposals per thread)
  const int blo = boff[b], bhi = boff[b + 1];
  const int i0 = tid * 32;
  unsigned mask = 0u;
  #pragma unroll
  for (int j = 0; j < 32; ++j) {
    const int off = poff[i0 + j];
    const int fp  = pidx[2 * off + 1];
    mask |= (fp >= blo && fp < bhi) ? (1u << j) : 0u;
  }
  const int cnt = __popc(mask);
  int sc = cnt;                    // inclusive wave scan
  #pragma unroll
  for (int d = 1; d < 64; d <<= 1) {
    const int v = __shfl_up(sc, d);
    if (lane >= d) sc += v;
  }
  if (lane == 63) wtot[wid] = sc;
  __syncthreads();
  int base = sc - cnt;
  #pragma unroll
  for (int w = 0; w < 4; ++w) if (w < wid) base += wtot[w];
  // bit-walk: stable batch-rank; scatter into this block's window
  {
    unsigned m = mask;
    int r = base;
    while (m) {
      const int j = __ffs(m) - 1;
      if (r >= r0 && r < r0 + MC) sSrow[r - r0] = i0 + j;
      ++r;
      m &= m - 1;
    }
  }

  // ---- issue layer-0 weight loads early (in flight during lang/pbuf work)
  float4 wstage[16];               // [t*8 + sp*2 + half]
  #pragma unroll
  for (int t = 0; t < 2; ++t) {
    const int o = (wid * 2 + t) * 16 + o16;
    #pragma unroll
    for (int sp = 0; sp < 4; ++sp) {
      const float* rp = Wf + (size_t)o * 384 + sp * 32 + g * 4;
      wstage[t * 8 + sp * 2]     = *reinterpret_cast<const float4*>(rp);
      wstage[t * 8 + sp * 2 + 1] = *reinterpret_cast<const float4*>(rp + 16);
    }
  }

  // ---- BN folds + W3 into pbuf (entries 128..1023)
  #pragma unroll
  for (int j = 128 + tid; j < 1024; j += 256) {
    const int arr = j >> 7, o = j & 127;
    float v;
    switch (arr) {
      case 1: v = b1[o]; break;
      case 2: v = g1[o] * rsqrtf(rv1[o] + EPS_); break;
      case 3: { const float s = g1[o] * rsqrtf(rv1[o] + EPS_);
                v = be1[o] - rm1[o] * s; } break;
      case 4: v = b2[o]; break;
      case 5: v = g2[o] * rsqrtf(rv2[o] + EPS_); break;
      case 6: { const float s = g2[o] * rsqrtf(rv2[o] + EPS_);
                v = be2[o] - rm2[o] * s; } break;
      default: v = W3[o]; break;
    }
    pbuf[j] = v;
  }

  // ---- lang projection for batch b: pbuf[o] = bf[o] + Wf[o,128:384].lang[b]
  if (tid < 128) {
    const int o = tid;
    float acc = 0.f;
    for (int l = 0; l < LANG_; l += 4) {
      const float4 w = *reinterpret_cast<const float4*>(Wf + o * 384 + 128 + l);
      const float4 e = *reinterpret_cast<const float4*>(langg + b * LANG_ + l);
      acc += w.x * e.x + w.y * e.y + w.z * e.z + w.w * e.w;
    }
    pbuf[o] = acc + bf[o];
  }
  __syncthreads();   // sSrow + pbuf ready

  // ---- gather feats (hi/lo split) into Xb: frag (s,gg) x col n
  {
    const int n = tid & 15, u = tid >> 4;   // u = sg in [0,16)
    const int s = u >> 2, gg = u & 3;
    const int srow = sSrow[n];
    const int k0 = s * 32 + gg * 4;
    float4 a = make_float4(0.f, 0.f, 0.f, 0.f), bq = a;
    if (srow >= 0) {
      a  = *reinterpret_cast<const float4*>(feats + (size_t)srow * M_ + k0);
      bq = *reinterpret_cast<const float4*>(feats + (size_t)srow * M_ + k0 + 16);
    }
    const float av[8] = {a.x, a.y, a.z, a.w, bq.x, bq.y, bq.z, bq.w};
    s16x8 hv, lv;
    #pragma unroll
    for (int e = 0; e < 8; ++e) {
      const unsigned short h = f2bf(av[e]);
      hv[e] = (short)h;
      lv[e] = (short)f2bf(av[e] - bf2f(h));
    }
    XbHi[u * 16 + n] = hv;
    XbLo[u * 16 + n] = lv;
  }
  __syncthreads();

  // ---- convert layer-0 weights into A-frags
  s16x8 A_[2][8];
  #pragma unroll
  for (int t = 0; t < 2; ++t)
    #pragma unroll
    for (int sp = 0; sp < 4; ++sp) {
      const float4 a = wstage[t * 8 + sp * 2], c = wstage[t * 8 + sp * 2 + 1];
      const float av[8] = {a.x, a.y, a.z, a.w, c.x, c.y, c.z, c.w};
      s16x8 hv, lv;
      #pragma unroll
      for (int e = 0; e < 8; ++e) {
        const unsigned short h = f2bf(av[e]);
        hv[e] = (short)h;
        lv[e] = (short)f2bf(av[e] - bf2f(h));
      }
      A_[t][sp] = hv;
      A_[t][4 + sp] = lv;
    }

  for (int L = 0; L < 3; ++L) {
    // B-frags from LDS into regs
    s16x8 Bh[4], Bl[4];
    #pragma unroll
    for (int s = 0; s < 4; ++s) {
      const int idx = (s * 4 + g) * 16 + o16;
      Bh[s] = XbHi[idx];
      Bl[s] = XbLo[idx];
    }
    __syncthreads();   // all waves done reading Xb before anyone overwrites

    // prefetch next layer fp32 weights (in flight during MFMAs)
    if (L < 2) {
      const float* Wn = (L == 0) ? W1 : W2;
      #pragma unroll
      for (int t = 0; t < 2; ++t) {
        const int o = (wid * 2 + t) * 16 + o16;
        #pragma unroll
        for (int sp = 0; sp < 4; ++sp) {
          const float* rp = Wn + (size_t)o * H_ + sp * 32 + g * 4;
          wstage[t * 8 + sp * 2]     = *reinterpret_cast<const float4*>(rp);
          wstage[t * 8 + sp * 2 + 1] = *reinterpret_cast<const float4*>(rp + 16);
        }
      }
    }

    f32x4 acc[2];
    acc[0] = (f32x4){0.f, 0.f, 0.f, 0.f};
    acc[1] = (f32x4){0.f, 0.f, 0.f, 0.f};

    // pass 1: [Whi|Wlo] . [Xhi;Xlo]
    #pragma unroll
    for (int sg = 0; sg < 8; ++sg) {
      const s16x8 bb = (sg < 4) ? Bh[sg] : Bl[sg - 4];
      #pragma unroll
      for (int t = 0; t < 2; ++t)
        acc[t] = __builtin_amdgcn_mfma_f32_16x16x32_bf16(A_[t][sg], bb, acc[t], 0, 0, 0);
    }
    // pass 2: [Whi|Wlo] . [Xlo;Xhi]
    #pragma unroll
    for (int sg = 0; sg < 8; ++sg) {
      const s16x8 bb = (sg < 4) ? Bl[sg] : Bh[sg - 4];
      #pragma unroll
      for (int t = 0; t < 2; ++t)
        acc[t] = __builtin_amdgcn_mfma_f32_16x16x32_bf16(A_[t][sg], bb, acc[t], 0, 0, 0);
    }

    if (L < 2) {
      // activation + split + write next-layer Xb (wave wid owns s=wid)
      s16x8 hv, lv;
      #pragma unroll
      for (int t = 0; t < 2; ++t)
        #pragma unroll
        for (int r = 0; r < 4; ++r) {
          const int o = (wid * 2 + t) * 16 + g * 4 + r;
          const float z = acc[t][r];
          float v;
          if (L == 0) v = fmaxf(z + pbuf[o], 0.f);
          else        v = fmaxf(z + pbuf[128 + o], 0.f) * pbuf[256 + o] + pbuf[384 + o];
          const unsigned short h = f2bf(v);
          hv[t * 4 + r] = (short)h;
          lv[t * 4 + r] = (short)f2bf(v - bf2f(h));
        }
      const int widx = (wid * 4 + g) * 16 + o16;
      XbHi[widx] = hv;
      XbLo[widx] = lv;
      __syncthreads();

      // convert prefetched next-layer weights into A-frags
      #pragma unroll
      for (int t = 0; t < 2; ++t)
        #pragma unroll
        for (int sp = 0; sp < 4; ++sp) {
          const float4 a = wstage[t * 8 + sp * 2], c = wstage[t * 8 + sp * 2 + 1];
          const float av[8] = {a.x, a.y, a.z, a.w, c.x, c.y, c.z, c.w};
          s16x8 h2, l2;
          #pragma unroll
          for (int e = 0; e < 8; ++e) {
            const unsigned short h = f2bf(av[e]);
            h2[e] = (short)h;
            l2[e] = (short)f2bf(av[e] - bf2f(h));
          }
          A_[t][sp] = h2;
          A_[t][4 + sp] = l2;
        }
    } else {
      // final: BN2 then dot with W3, reduce over o-groups
      float p0 = 0.f;
      #pragma unroll
      for (int t = 0; t < 2; ++t)
        #pragma unroll
        for (int r = 0; r < 4; ++r) {
          const int o = (wid * 2 + t) * 16 + g * 4 + r;
          const float w3 = pbuf[896 + o];
          const float bb2 = pbuf[512 + o], ss2 = pbuf[640 + o], tt2 = pbuf[768 + o];
          p0 += w3 * (fmaxf(acc[t][r] + bb2, 0.f) * ss2 + tt2);
        }
      p0 += __shfl_xor(p0, 16);
      p0 += __shfl_xor(p0, 32);
      if (lane < 16) outp[wid * 16 + lane] = p0;
      __syncthreads();
      if (tid < 16)
        out[q0 + tid] = outp[tid] + outp[16 + tid] + outp[32 + tid] + outp[48 + tid] + b3[0];
    }
  }
}

// ---------------------------------------------------------------------------
extern "C" void kernel_launch(void* const* d_in, const int* in_sizes, int n_in,
                              void* d_out, int out_size, void* d_ws, size_t ws_size,
                              hipStream_t stream) {
  const float* feats = (const float*)d_in[0];
  const int*   pidx  = (const int*)d_in[1];
  const int*   poff  = (const int*)d_in[2];
  const int*   boff  = (const int*)d_in[3];
  const float* lang  = (const float*)d_in[4];
  const float* Wf    = (const float*)d_in[5];
  const float* bf    = (const float*)d_in[6];
  const float* W1    = (const float*)d_in[7];
  const float* b1    = (const float*)d_in[8];
  const float* g1    = (const float*)d_in[9];
  const float* be1   = (const float*)d_in[10];
  const float* rm1   = (const float*)d_in[11];
  const float* rv1   = (const float*)d_in[12];
  const float* W2    = (const float*)d_in[13];
  const float* b2    = (const float*)d_in[14];
  const float* g2    = (const float*)d_in[15];
  const float* be2   = (const float*)d_in[16];
  const float* rm2   = (const float*)d_in[17];
  const float* rv2   = (const float*)d_in[18];
  const float* W3    = (const float*)d_in[19];
  const float* b3    = (const float*)d_in[20];
  float* out = (float*)d_out;

  hipLaunchKernelGGL(k_fused, dim3(NBLK), dim3(256), 0, stream,
                     feats, pidx, poff, boff, lang, Wf, bf,
                     W1, b1, g1, be1, rm1, rv1,
                     W2, b2, g2, be2, rm2, rv2, W3, b3, out);
}

// Round 6
// 24.344 us; speedup vs baseline: 1.9744x; 1.9744x over previous
//
#include <hip/hip_runtime.h>
#include <math.h>

#define B_    32
#define PPB   256
#define N_    (B_*PPB)     // 8192 proposals / padded slots
#define M_    128
#define LANG_ 256
#define H_    128
#define EPS_  1e-5f
#define MC    16           // columns per MLP block
#define WA_OFF 120832      // byte offset of Wa in workspace (16B aligned)

typedef __attribute__((ext_vector_type(8))) short s16x8;
typedef __attribute__((ext_vector_type(4))) float f32x4;

static __device__ __forceinline__ unsigned short f2bf(float x) {
  unsigned int u = __float_as_uint(x);
  unsigned int r = (u + 0x7fff + ((u >> 16) & 1)) >> 16;
  return (unsigned short)r;
}
static __device__ __forceinline__ float bf2f(unsigned short h) {
  return __uint_as_float(((unsigned int)h) << 16);
}

// ---------------------------------------------------------------------------
// Kernel A: batch id + within-chunk stable rank (ballot) + chunk histograms
// + lang projection (2 threads/output) + frag-major hi/lo bf16 weights Wa.
// One block per 256-proposal chunk.
// ---------------------------------------------------------------------------
__global__ __launch_bounds__(256) void k_map_a(
    const int* __restrict__ pidx, const int* __restrict__ poff,
    const int* __restrict__ boff, int* __restrict__ bid_g,
    int* __restrict__ wrank_g, int* __restrict__ hist_g,
    int* __restrict__ src_of_dest,
    const float* __restrict__ Wf, const float* __restrict__ lang,
    float* __restrict__ lp,
    const float* __restrict__ W1, const float* __restrict__ W2,
    unsigned short* __restrict__ wa)
{
  __shared__ int sb[33];
  __shared__ int wh[4][32];    // per-wave per-bin counts
  const int tid = threadIdx.x;
  const int i = blockIdx.x * 256 + tid;
  const int lane = tid & 63, wid = tid >> 6;
  if (tid < 33) sb[tid] = boff[tid];
  __syncthreads();
  const int off = poff[i];
  const int fp  = pidx[2 * off + 1];
  int cnt = 0;
  #pragma unroll
  for (int j = 0; j < 33; ++j) cnt += (sb[j] <= fp) ? 1 : 0;
  int bd = cnt - 1;
  bd = bd < 0 ? 0 : (bd > 31 ? 31 : bd);
  bid_g[i] = bd;
  src_of_dest[i] = -1;

  // ballot-based within-chunk stable rank
  unsigned long long mym = 0;
  #pragma unroll
  for (int k = 0; k < 32; ++k) {
    const unsigned long long m = __ballot(bd == k);
    if (bd == k) mym = m;
    if (lane == k) wh[wid][k] = __popcll(m);
  }
  const int rw = __popcll(mym & ((1ull << lane) - 1ull));
  __syncthreads();
  int base = 0;
  #pragma unroll
  for (int w = 0; w < 4; ++w) if (w < wid) base += wh[w][bd];
  wrank_g[i] = base + rw;
  if (tid < 32) hist_g[blockIdx.x * 32 + tid] =
      wh[0][tid] + wh[1][tid] + wh[2][tid] + wh[3][tid];

  // lang projection for batch = blockIdx.x: 2 threads per output channel
  {
    const int o = tid >> 1, hf = tid & 1;
    float acc = 0.f;
    const int l0 = hf * 128;
    #pragma unroll 8
    for (int l = l0; l < l0 + 128; l += 4) {
      const float4 w = *reinterpret_cast<const float4*>(Wf + o * 384 + 128 + l);
      const float4 e = *reinterpret_cast<const float4*>(lang + blockIdx.x * LANG_ + l);
      acc += w.x * e.x + w.y * e.y + w.z * e.z + w.w * e.w;
    }
    acc += __shfl_xor(acc, 1);
    if (hf == 0) lp[blockIdx.x * H_ + o] = acc;
  }

  // build Wa: 192 frag-groups over 128 waves
  for (int G = blockIdx.x * 4 + wid; G < 192; G += 128) {
    const int L = G >> 6, s = (G >> 3) & 7, t = G & 7;
    const float* Wsrc; int str;
    if (L == 0)      { Wsrc = Wf; str = 384; }
    else if (L == 1) { Wsrc = W1; str = H_; }
    else             { Wsrc = W2; str = H_; }
    const int o = t * 16 + (lane & 15), g = lane >> 4, sp = s & 3;
    const bool hi = (s < 4);
    const float* rowp = Wsrc + (size_t)o * str + sp * 32 + g * 4;
    const float4 a = *reinterpret_cast<const float4*>(rowp);
    const float4 bq = *reinterpret_cast<const float4*>(rowp + 16);
    const float av[8] = {a.x, a.y, a.z, a.w, bq.x, bq.y, bq.z, bq.w};
    s16x8 v;
    #pragma unroll
    for (int e = 0; e < 8; ++e) {
      const unsigned short h = f2bf(av[e]);
      v[e] = (short)(hi ? h : f2bf(av[e] - bf2f(h)));
    }
    *reinterpret_cast<s16x8*>(wa + (size_t)G * 512 + lane * 8) = v;
  }
}

// ---------------------------------------------------------------------------
// Kernel B (NEW, parallel): 32 blocks, one per chunk. 256 threads jointly
// compute this chunk's per-bin exclusive prefix over earlier chunks (<=4
// independent coalesced loads/thread + LDS tree), then scatter inverse map.
// Replaces the single-block serial-scan kernel (~10-12 us -> ~1 us).
// ---------------------------------------------------------------------------
__global__ __launch_bounds__(256) void k_scat(
    const int* __restrict__ bid_g, const int* __restrict__ wrank_g,
    const int* __restrict__ hist_g, int* __restrict__ src_of_dest)
{
  __shared__ int sh[8][32];
  __shared__ int cb[32];
  const int c = blockIdx.x, tid = threadIdx.x;
  const int u = tid >> 5, bin = tid & 31;
  int run = 0;
  #pragma unroll
  for (int p = 0; p < 4; ++p) {
    const int cc = u + 8 * p;
    if (cc < c) run += hist_g[cc * 32 + bin];
  }
  sh[u][bin] = run;
  __syncthreads();
  if (tid < 32) {
    int s = 0;
    #pragma unroll
    for (int w = 0; w < 8; ++w) s += sh[w][tid];
    cb[tid] = s;
  }
  __syncthreads();
  const int i = c * 256 + tid;
  const int bd = bid_g[i];
  const int rank = cb[bd] + wrank_g[i];
  if (rank < PPB) src_of_dest[bd * PPB + rank] = i;   // OOB dropped (.at.set)
}

// ---------------------------------------------------------------------------
// Kernel D: MFMA MLP. 512 blocks x 256 threads (2 blocks/CU), 16 cols/block.
// hi/lo bf16 split, 2 K=256 passes/layer. A-frags from pre-converted wa
// (coalesced s16x8 loads), next layer prefetched during current MFMAs.
// Fully unrolled layers -> static register indexing, no scratch.
// ---------------------------------------------------------------------------
#define MFMA_LAYER(Aarr)                                                     \
  {                                                                          \
    _Pragma("unroll")                                                        \
    for (int sg = 0; sg < 8; ++sg) {                                         \
      const s16x8 bb = (sg < 4) ? Bh[sg] : Bl[sg - 4];                       \
      acc[0] = __builtin_amdgcn_mfma_f32_16x16x32_bf16(Aarr[0][sg], bb, acc[0], 0, 0, 0); \
      acc[1] = __builtin_amdgcn_mfma_f32_16x16x32_bf16(Aarr[1][sg], bb, acc[1], 0, 0, 0); \
    }                                                                        \
    _Pragma("unroll")                                                        \
    for (int sg = 0; sg < 8; ++sg) {                                         \
      const s16x8 bb = (sg < 4) ? Bl[sg] : Bh[sg - 4];                       \
      acc[0] = __builtin_amdgcn_mfma_f32_16x16x32_bf16(Aarr[0][sg], bb, acc[0], 0, 0, 0); \
      acc[1] = __builtin_amdgcn_mfma_f32_16x16x32_bf16(Aarr[1][sg], bb, acc[1], 0, 0, 0); \
    }                                                                        \
  }

#define READ_B()                                                             \
  {                                                                          \
    _Pragma("unroll")                                                        \
    for (int s = 0; s < 4; ++s) {                                            \
      const int idx = (s * 4 + g) * 16 + o16;                                \
      Bh[s] = XbHi[idx];                                                     \
      Bl[s] = XbLo[idx];                                                     \
    }                                                                        \
  }

#define LOAD_A(Aarr, LL)                                                     \
  {                                                                          \
    _Pragma("unroll")                                                        \
    for (int t = 0; t < 2; ++t)                                              \
      _Pragma("unroll")                                                      \
      for (int s = 0; s < 8; ++s)                                            \
        Aarr[t][s] = *reinterpret_cast<const s16x8*>(                        \
            wa + (size_t)(((LL) * 8 + s) * 8 + (wid * 2 + t)) * 512 + lane * 8); \
  }

__global__ __launch_bounds__(256, 2) void k_mlp(
    const float* __restrict__ feats,
    const unsigned short* __restrict__ wa,
    const float* __restrict__ bf, const float* __restrict__ b1,
    const float* __restrict__ g1, const float* __restrict__ be1,
    const float* __restrict__ rm1, const float* __restrict__ rv1,
    const float* __restrict__ b2, const float* __restrict__ g2,
    const float* __restrict__ be2, const float* __restrict__ rm2,
    const float* __restrict__ rv2,
    const float* __restrict__ W3, const float* __restrict__ b3,
    const int* __restrict__ srcmap, const float* __restrict__ lpg,
    float* __restrict__ out)
{
  __shared__ s16x8 XbHi[256];      // [sg16][n16] frags (4 KB)
  __shared__ s16x8 XbLo[256];      // (4 KB)
  __shared__ float pbuf[1024];
  __shared__ float outp[64];

  const int tid = threadIdx.x;
  const int lane = tid & 63, wid = tid >> 6;
  const int o16 = lane & 15, g = lane >> 4;
  const int q0 = blockIdx.x * MC;
  const int b = blockIdx.x >> 4;   // 16 blocks per batch

  // ---- issue L0 A-frag loads first (in flight under pbuf + feats staging)
  s16x8 A0[2][8], A1[2][8], A2[2][8];
  LOAD_A(A0, 0);

  // ---- params into LDS (BN folded): [0]=bf+lp,[1]=b1,[2]=s1,[3]=t1,
  //      [4]=b2,[5]=s2,[6]=t2,[7]=W3
  #pragma unroll
  for (int j = tid; j < 1024; j += 256) {
    const int arr = j >> 7, o = j & 127;
    float v;
    switch (arr) {
      case 0: v = bf[o] + lpg[b * H_ + o]; break;
      case 1: v = b1[o]; break;
      case 2: v = g1[o] * rsqrtf(rv1[o] + EPS_); break;
      case 3: { const float s = g1[o] * rsqrtf(rv1[o] + EPS_);
                v = be1[o] - rm1[o] * s; } break;
      case 4: v = b2[o]; break;
      case 5: v = g2[o] * rsqrtf(rv2[o] + EPS_); break;
      case 6: { const float s = g2[o] * rsqrtf(rv2[o] + EPS_);
                v = be2[o] - rm2[o] * s; } break;
      default: v = W3[o]; break;
    }
    pbuf[j] = v;
  }

  // ---- gather feats (hi/lo split) into Xb: frag (s,gg) x col n
  {
    const int n = tid & 15, u = tid >> 4;
    const int s = u >> 2, gg = u & 3;
    const int srow = srcmap[q0 + n];
    const int k0 = s * 32 + gg * 4;
    float4 a = make_float4(0.f, 0.f, 0.f, 0.f), bq = a;
    if (srow >= 0) {
      a  = *reinterpret_cast<const float4*>(feats + (size_t)srow * M_ + k0);
      bq = *reinterpret_cast<const float4*>(feats + (size_t)srow * M_ + k0 + 16);
    }
    const float av[8] = {a.x, a.y, a.z, a.w, bq.x, bq.y, bq.z, bq.w};
    s16x8 hv, lv;
    #pragma unroll
    for (int e = 0; e < 8; ++e) {
      const unsigned short h = f2bf(av[e]);
      hv[e] = (short)h;
      lv[e] = (short)f2bf(av[e] - bf2f(h));
    }
    XbHi[u * 16 + n] = hv;
    XbLo[u * 16 + n] = lv;
  }
  __syncthreads();

  f32x4 acc[2];
  s16x8 Bh[4], Bl[4];

  // ================= Layer 0 =================
  READ_B();
  __syncthreads();
  LOAD_A(A1, 1);                   // prefetch next layer
  acc[0] = (f32x4){0.f, 0.f, 0.f, 0.f};
  acc[1] = (f32x4){0.f, 0.f, 0.f, 0.f};
  MFMA_LAYER(A0);
  {
    s16x8 hv, lv;
    #pragma unroll
    for (int t = 0; t < 2; ++t)
      #pragma unroll
      for (int r = 0; r < 4; ++r) {
        const int o = (wid * 2 + t) * 16 + g * 4 + r;
        const float v = fmaxf(acc[t][r] + pbuf[o], 0.f);
        const unsigned short h = f2bf(v);
        hv[t * 4 + r] = (short)h;
        lv[t * 4 + r] = (short)f2bf(v - bf2f(h));
      }
    const int widx = (wid * 4 + g) * 16 + o16;
    XbHi[widx] = hv;
    XbLo[widx] = lv;
  }
  __syncthreads();

  // ================= Layer 1 =================
  READ_B();
  __syncthreads();
  LOAD_A(A2, 2);                   // prefetch final layer
  acc[0] = (f32x4){0.f, 0.f, 0.f, 0.f};
  acc[1] = (f32x4){0.f, 0.f, 0.f, 0.f};
  MFMA_LAYER(A1);
  {
    s16x8 hv, lv;
    #pragma unroll
    for (int t = 0; t < 2; ++t)
      #pragma unroll
      for (int r = 0; r < 4; ++r) {
        const int o = (wid * 2 + t) * 16 + g * 4 + r;
        const float v = fmaxf(acc[t][r] + pbuf[128 + o], 0.f) * pbuf[256 + o]
                        + pbuf[384 + o];
        const unsigned short h = f2bf(v);
        hv[t * 4 + r] = (short)h;
        lv[t * 4 + r] = (short)f2bf(v - bf2f(h));
      }
    const int widx = (wid * 4 + g) * 16 + o16;
    XbHi[widx] = hv;
    XbLo[widx] = lv;
  }
  __syncthreads();

  // ================= Layer 2 + epilogue =================
  READ_B();
  acc[0] = (f32x4){0.f, 0.f, 0.f, 0.f};
  acc[1] = (f32x4){0.f, 0.f, 0.f, 0.f};
  MFMA_LAYER(A2);
  {
    float p0 = 0.f;
    #pragma unroll
    for (int t = 0; t < 2; ++t)
      #pragma unroll
      for (int r = 0; r < 4; ++r) {
        const int o = (wid * 2 + t) * 16 + g * 4 + r;
        p0 += pbuf[896 + o] *
              (fmaxf(acc[t][r] + pbuf[512 + o], 0.f) * pbuf[640 + o] + pbuf[768 + o]);
      }
    p0 += __shfl_xor(p0, 16);
    p0 += __shfl_xor(p0, 32);
    if (lane < 16) outp[wid * 16 + lane] = p0;
    __syncthreads();
    if (tid < 16)
      out[q0 + tid] = outp[tid] + outp[16 + tid] + outp[32 + tid] + outp[48 + tid] + b3[0];
  }
}

// ---------------------------------------------------------------------------
extern "C" void kernel_launch(void* const* d_in, const int* in_sizes, int n_in,
                              void* d_out, int out_size, void* d_ws, size_t ws_size,
                              hipStream_t stream) {
  const float* feats = (const float*)d_in[0];
  const int*   pidx  = (const int*)d_in[1];
  const int*   poff  = (const int*)d_in[2];
  const int*   boff  = (const int*)d_in[3];
  const float* lang  = (const float*)d_in[4];
  const float* Wf    = (const float*)d_in[5];
  const float* bf    = (const float*)d_in[6];
  const float* W1    = (const float*)d_in[7];
  const float* b1    = (const float*)d_in[8];
  const float* g1    = (const float*)d_in[9];
  const float* be1   = (const float*)d_in[10];
  const float* rm1   = (const float*)d_in[11];
  const float* rv1   = (const float*)d_in[12];
  const float* W2    = (const float*)d_in[13];
  const float* b2    = (const float*)d_in[14];
  const float* g2    = (const float*)d_in[15];
  const float* be2   = (const float*)d_in[16];
  const float* rm2   = (const float*)d_in[17];
  const float* rv2   = (const float*)d_in[18];
  const float* W3    = (const float*)d_in[19];
  const float* b3    = (const float*)d_in[20];
  float* out = (float*)d_out;

  int* srcmap = (int*)d_ws;                  // 32768 B
  int* bidp   = srcmap + N_;                 // 32768 B
  int* wrank  = bidp + N_;                   // 32768 B
  int* hist   = wrank + N_;                  // 4096 B
  float* lp = (float*)(hist + 32 * 32);      // 16384 B
  unsigned short* wa = (unsigned short*)((char*)d_ws + WA_OFF);  // 196608 B

  hipLaunchKernelGGL(k_map_a, dim3(32), dim3(256), 0, stream,
                     pidx, poff, boff, bidp, wrank, hist, srcmap,
                     Wf, lang, lp, W1, W2, wa);
  hipLaunchKernelGGL(k_scat, dim3(32), dim3(256), 0, stream,
                     bidp, wrank, hist, srcmap);
  hipLaunchKernelGGL(k_mlp, dim3(N_ / MC), dim3(256), 0, stream,
                     feats, wa, bf, b1, g1, be1, rm1, rv1,
                     b2, g2, be2, rm2, rv2, W3, b3, srcmap, lp, out);
}